// Round 13
// baseline (228.216 us; speedup 1.0000x reference)
//
#include <hip/hip_runtime.h>

#define Bd 4
#define Hd 8
#define Ld 2048
#define Dd 64
#define Ud 40
#define NTOP 40
#define NCHUNK 64
#define CSZ 32   // Ld / NCHUNK

#define NS 16     // k-splits for flash attention
#define FTILE 128 // Ld / NS keys per split
#define QSTR 68   // padded LDS stride (floats) for q rows
#define KSTR 68   // padded LDS stride (floats) for k/v rows
#define PSTR 132  // padded LDS stride for p rows

// ---------------------------------------------------------------------------
// Phase 1 (grid 4096, coarse role split — proven in R9/R12):
//   role A (blocks 0..2047)   = compute_M, transposed lanes: lane (s,h)
//       computes the FULL dot for (sample j*8+s, head h) — no per-sample
//       shuffle reduce; one stride-8 butterfly at the end.
//   role B (blocks 2048..4095) = chunk_sums of V.
// ---------------------------------------------------------------------------
__global__ __launch_bounds__(256, 4) void phase1_kernel(
    const float* __restrict__ q, const float* __restrict__ k,
    const float* __restrict__ v, const int* __restrict__ ridx,
    float* __restrict__ M, float* __restrict__ csum) {
  __shared__ float red[256];
  int tid = threadIdx.x;
  if (blockIdx.x < 2048) {
    // ---- compute_M ----
    const int nblk = 2048;
    int orig = blockIdx.x;
    int bid = (orig & 7) * (nblk >> 3) + (orig >> 3);  // XCD swizzle
    int gw = bid * 4 + (tid >> 6);
    int lane = tid & 63;
    int s = lane >> 3;  // sample slot 0..7
    int h = lane & 7;   // head
    int b = gw >> 11;
    int l = gw & (Ld - 1);

    // Q row for this head: 64 floats in 16 float4 regs (8-way broadcast).
    const float4* qr4 = reinterpret_cast<const float4*>(
        q + ((size_t)b * Ld + l) * (Hd * Dd) + h * Dd);
    float4 qreg[16];
#pragma unroll
    for (int i = 0; i < 16; ++i) qreg[i] = qr4[i];

    int rv = 0;
    if (lane < Ud) rv = ridx[l * Ud + lane];
    const float* kb = k + (size_t)b * Ld * (Hd * Dd);

    float mx = -INFINITY, sm = 0.f;
#pragma unroll
    for (int j = 0; j < Ud / 8; ++j) {
      int row = __shfl(rv, j * 8 + s);  // this lane's sample row
      const float4* kr4 = reinterpret_cast<const float4*>(
          kb + (size_t)row * (Hd * Dd) + h * Dd);
      float4 acc = {0.f, 0.f, 0.f, 0.f};
#pragma unroll
      for (int i = 0; i < 16; ++i) {
        float4 kv = kr4[i];
        acc.x += qreg[i].x * kv.x;
        acc.y += qreg[i].y * kv.y;
        acc.z += qreg[i].z * kv.z;
        acc.w += qreg[i].w * kv.w;
      }
      float d = (acc.x + acc.y) + (acc.z + acc.w);
      mx = fmaxf(mx, d);
      sm += d;
    }
    // combine the 8 sample-slots; lanes at stride 8 share the same head.
#pragma unroll
    for (int off = 8; off < 64; off <<= 1) {
      mx = fmaxf(mx, __shfl_xor(mx, off));
      sm += __shfl_xor(sm, off);
    }
    if (s == 0)
      M[((size_t)b * Hd + h) * Ld + l] = mx - sm * (1.0f / (float)Ld);
  } else {
    // ---- chunk sums of V ----
    int n = blockIdx.x - 2048;  // 0..2047 = bh*NCHUNK + c
    int c = n & (NCHUNK - 1), bh = n >> 6;
    int b = bh >> 3, h = bh & 7;
    int d = tid & 63, jg = tid >> 6;
    int t0 = c * CSZ;
    float s = 0.f;
#pragma unroll
    for (int j = jg; j < CSZ; j += 4)
      s += v[(((size_t)b * Ld + t0 + j) * Hd + h) * Dd + d];
    red[tid] = s;
    __syncthreads();
    if (jg == 0)
      csum[(size_t)n * Dd + d] =
          red[d] + red[64 + d] + red[128 + d] + red[192 + d];
  }
}

// ---------------------------------------------------------------------------
// Phase 2: role A (blocks 0..31) = top-40 per (b,h) (per-lane top-3 cache);
//          role B (blocks 32..63) = exclusive scan of chunk sums.
// ---------------------------------------------------------------------------
__global__ __launch_bounds__(64) void phase2_kernel(const float* __restrict__ M,
                                                    int* __restrict__ topIdx,
                                                    float* __restrict__ csum) {
  int lane = threadIdx.x;
  if (blockIdx.x < 32) {
    int bh = blockIdx.x;
    const float* mrow = M + (size_t)bh * Ld;

    unsigned int key[32];
#pragma unroll
    for (int j = 0; j < 32; ++j) {
      unsigned int bits = __float_as_uint(mrow[lane + j * 64]);
      key[j] = (bits & 0x80000000u) ? ~bits : (bits | 0x80000000u);
    }

    const int ISENT = 1 << 30;
    unsigned int k0 = 0u, k1c = 0u, k2c = 0u;
    int i0 = ISENT, i1c = ISENT, i2c = ISENT;
#pragma unroll
    for (int j = 0; j < 32; ++j) {
      unsigned int kj = key[j];
      int idx = lane + j * 64;
      if (kj > k0) {
        k2c = k1c; i2c = i1c; k1c = k0; i1c = i0; k0 = kj; i0 = idx;
      } else if (kj > k1c) {
        k2c = k1c; i2c = i1c; k1c = kj; i1c = idx;
      } else if (kj > k2c) {
        k2c = kj; i2c = idx;
      }
    }

    for (int it = 0; it < NTOP; ++it) {
      unsigned int wk = k0;
      int wi = i0;
#pragma unroll
      for (int off = 1; off < 64; off <<= 1) {
        unsigned int ok = __shfl_xor(wk, off);
        int oi = __shfl_xor(wi, off);
        if (ok > wk || (ok == wk && oi < wi)) { wk = ok; wi = oi; }
      }
      if (lane == 0) topIdx[bh * NTOP + it] = wi;
      if (wi == i0) {
        k0 = k1c; i0 = i1c; k1c = k2c; i1c = i2c; k2c = 0u; i2c = ISENT;
        if (k0 == 0u) {
          i0 = ISENT; i1c = ISENT; i2c = ISENT;
#pragma unroll
          for (int j = 0; j < 32; ++j) {
            unsigned int kj = key[j];
            int idx = lane + j * 64;
            bool valid = (kj < wk) || (kj == wk && idx > wi);
            kj = valid ? kj : 0u;
            if (kj > k0) {
              k2c = k1c; i2c = i1c; k1c = k0; i1c = i0; k0 = kj; i0 = idx;
            } else if (kj > k1c) {
              k2c = k1c; i2c = i1c; k1c = kj; i1c = idx;
            } else if (kj > k2c) {
              k2c = kj; i2c = idx;
            }
          }
        }
      }
    }
  } else {
    int bh = blockIdx.x - 32;
    float acc = 0.f;
#pragma unroll 8
    for (int c = 0; c < NCHUNK; ++c) {
      size_t i = ((size_t)bh * NCHUNK + c) * Dd + lane;
      float s = csum[i];
      csum[i] = acc;
      acc += s;
    }
  }
}

// ---------------------------------------------------------------------------
// Phase 3 (grid 1024, coarse role split):
//   role A (blocks 0..511)   = fused split-K flash attention
//   role B (blocks 512..1023) = cumsum write (4 waves x one 32-row chunk).
// ---------------------------------------------------------------------------
__global__ __launch_bounds__(256) void phase3_kernel(
    const float* __restrict__ q, const float* __restrict__ k,
    const float* __restrict__ v, const int* __restrict__ topIdx,
    const float* __restrict__ csum, float* __restrict__ out,
    float* __restrict__ Opart, float* __restrict__ mS,
    float* __restrict__ sS) {
  __shared__ float qs[NTOP * QSTR];
  __shared__ float ks[FTILE * KSTR];
  __shared__ float p[NTOP * PSTR];
  __shared__ int ts[NTOP];
  int tid = threadIdx.x;

  if (blockIdx.x >= 512) {
    // ---- cumsum write: 4 waves x one 32-row chunk each ----
    int m = blockIdx.x - 512;
    int lane = tid & 63, w = tid >> 6;
    int blk = m * 4 + w;  // 0..2047 = bh*NCHUNK + c
    int c = blk & (NCHUNK - 1), bh = blk >> 6;
    int b = bh >> 3, h = bh & 7;
    float acc = csum[(size_t)blk * Dd + lane];
    int t0 = c * CSZ;
    const float* vp = v + (((size_t)b * Ld + t0) * Hd + h) * Dd + lane;
    float* op = out + (((size_t)b * Ld + t0) * Hd + h) * Dd + lane;
#pragma unroll 8
    for (int j = 0; j < CSZ; ++j) {
      acc += vp[(size_t)j * (Hd * Dd)];
      op[(size_t)j * (Hd * Dd)] = acc;
    }
    return;
  }

  // ---- flash attention split ----
  int split = blockIdx.x % NS;
  int bh = blockIdx.x / NS;
  int b = bh >> 3, h = bh & 7;
  int k0 = split * FTILE;

  if (tid < NTOP) ts[tid] = topIdx[bh * NTOP + tid];
  __syncthreads();

  for (int i = tid; i < NTOP * 16; i += 256) {
    int u = i >> 4, ps = i & 15;
    float4 qv = reinterpret_cast<const float4*>(
        q + (((size_t)b * Ld + ts[u]) * Hd + h) * Dd)[ps];
    *reinterpret_cast<float4*>(&qs[u * QSTR + ps * 4]) = qv;
  }
  for (int i = tid; i < FTILE * 16; i += 256) {
    int r = i >> 4, ps = i & 15;
    float4 kv = reinterpret_cast<const float4*>(
        k + (((size_t)b * Ld + k0 + r) * Hd + h) * Dd)[ps];
    *reinterpret_cast<float4*>(&ks[r * KSTR + ps * 4]) = kv;
  }
  __syncthreads();

  int ug = tid & 7, kg = tid >> 3;
  int ub = ug * 5, kb = kg * 4;
  {
    float acc[5][4] = {};
    for (int dd = 0; dd < Dd; dd += 4) {
      float4 kv[4], qv[5];
#pragma unroll
      for (int i = 0; i < 4; ++i)
        kv[i] = *reinterpret_cast<const float4*>(&ks[(kb + i) * KSTR + dd]);
#pragma unroll
      for (int i = 0; i < 5; ++i)
        qv[i] = *reinterpret_cast<const float4*>(&qs[(ub + i) * QSTR + dd]);
#pragma unroll
      for (int ui = 0; ui < 5; ++ui)
#pragma unroll
        for (int ki = 0; ki < 4; ++ki)
          acc[ui][ki] += qv[ui].x * kv[ki].x + qv[ui].y * kv[ki].y +
                         qv[ui].z * kv[ki].z + qv[ui].w * kv[ki].w;
    }
#pragma unroll
    for (int ui = 0; ui < 5; ++ui) {
      int u = ub + ui;
      int t = ts[u];
      float4 o;
      o.x = (k0 + kb + 0 <= t) ? acc[ui][0] * 0.125f : -INFINITY;
      o.y = (k0 + kb + 1 <= t) ? acc[ui][1] * 0.125f : -INFINITY;
      o.z = (k0 + kb + 2 <= t) ? acc[ui][2] * 0.125f : -INFINITY;
      o.w = (k0 + kb + 3 <= t) ? acc[ui][3] * 0.125f : -INFINITY;
      *reinterpret_cast<float4*>(&p[u * PSTR + kb]) = o;
    }
  }
  __syncthreads();

  // V tile load (into ks) overlapped with per-row softmax stats
  for (int i = tid; i < FTILE * 16; i += 256) {
    int r = i >> 4, ps = i & 15;
    float4 vv = reinterpret_cast<const float4*>(
        v + (((size_t)b * Ld + k0 + r) * Hd + h) * Dd)[ps];
    *reinterpret_cast<float4*>(&ks[r * KSTR + ps * 4]) = vv;
  }
  if (tid < NTOP * 4) {
    int u = tid >> 2, l4 = tid & 3;
    float* pr = p + u * PSTR;
    float mx = -1e30f;
#pragma unroll 8
    for (int j = l4; j < FTILE; j += 4) mx = fmaxf(mx, pr[j]);
    mx = fmaxf(mx, __shfl_xor(mx, 1));
    mx = fmaxf(mx, __shfl_xor(mx, 2));
    float sum = 0.f;
#pragma unroll 8
    for (int j = l4; j < FTILE; j += 4) {
      float pe = __expf(pr[j] - mx);
      pr[j] = pe;
      sum += pe;
    }
    sum += __shfl_xor(sum, 1);
    sum += __shfl_xor(sum, 2);
    if (l4 == 0) {
      mS[((size_t)bh * NS + split) * NTOP + u] = mx;
      sS[((size_t)bh * NS + split) * NTOP + u] = sum;
    }
  }
  __syncthreads();

  int ug2 = tid >> 5, dg = tid & 31;
  int ub2 = ug2 * 5, d2 = dg * 2;
  float acc[5][2] = {};
#pragma unroll 4
  for (int kk = 0; kk < FTILE; ++kk) {
    float2 vv = *reinterpret_cast<const float2*>(&ks[kk * KSTR + d2]);
#pragma unroll
    for (int i = 0; i < 5; ++i) {
      float pe = p[(ub2 + i) * PSTR + kk];
      acc[i][0] += pe * vv.x;
      acc[i][1] += pe * vv.y;
    }
  }
  float* ob = Opart + ((size_t)bh * NS + split) * (NTOP * Dd);
#pragma unroll
  for (int i = 0; i < 5; ++i)
    *reinterpret_cast<float2*>(&ob[(ub2 + i) * Dd + d2]) =
        make_float2(acc[i][0], acc[i][1]);
}

// ---------------------------------------------------------------------------
// Phase 4: LSE combine across NS splits + scatter-overwrite output rows.
// ---------------------------------------------------------------------------
__global__ __launch_bounds__(64) void flash_combine_kernel(
    const float* __restrict__ Opart, const float* __restrict__ mS,
    const float* __restrict__ sS, const int* __restrict__ topIdx,
    float* __restrict__ out) {
  int row = blockIdx.x;
  int u = row % NTOP, bh = row / NTOP;
  int b = bh >> 3, h = bh & 7;
  int d = threadIdx.x;
  int t = topIdx[row];

  float mg = -1e30f;
#pragma unroll
  for (int s = 0; s < NS; ++s)
    mg = fmaxf(mg, mS[((size_t)bh * NS + s) * NTOP + u]);
  float den = 0.f, o = 0.f;
#pragma unroll
  for (int s = 0; s < NS; ++s) {
    float w = __expf(mS[((size_t)bh * NS + s) * NTOP + u] - mg);
    den += w * sS[((size_t)bh * NS + s) * NTOP + u];
    o += w * Opart[(((size_t)bh * NS + s) * NTOP + u) * Dd + d];
  }
  out[(((size_t)b * Ld + t) * Hd + h) * Dd + d] = o / den;
}

// ---------------------------------------------------------------------------
// Fallback pieces (ws too small): standalone cumsum write + simple attention.
// ---------------------------------------------------------------------------
__global__ void cumsum_write_kernel(const float* __restrict__ v,
                                    const float* __restrict__ csum,
                                    float* __restrict__ out) {
  int blk = blockIdx.x;
  int c = blk & (NCHUNK - 1), bh = blk >> 6;
  int b = bh >> 3, h = bh & 7;
  int d = threadIdx.x;
  float acc = csum[(size_t)blk * Dd + d];
  int t0 = c * CSZ;
#pragma unroll 8
  for (int j = 0; j < CSZ; ++j) {
    size_t idx = (((size_t)b * Ld + t0 + j) * Hd + h) * Dd + d;
    acc += v[idx];
    out[idx] = acc;
  }
}

__global__ void attn_update_kernel(const float* __restrict__ q,
                                   const float* __restrict__ k,
                                   const float* __restrict__ v,
                                   const int* __restrict__ topIdx,
                                   float* __restrict__ out) {
  __shared__ float sc[Ld];
  __shared__ float qs[Dd];
  __shared__ float red[256];
  int tid = threadIdx.x;
  int bh = blockIdx.x / NTOP;
  int b = bh >> 3, h = bh & 7;
  int t = topIdx[blockIdx.x];

  if (tid < Dd) qs[tid] = q[(((size_t)b * Ld + t) * Hd + h) * Dd + tid];
  __syncthreads();

  int nk = t + 1;
  const float4* qv4 = reinterpret_cast<const float4*>(qs);
  float lmax = -INFINITY;
  for (int kk = tid; kk < nk; kk += 256) {
    const float4* kr = reinterpret_cast<const float4*>(
        k + (((size_t)b * Ld + kk) * Hd + h) * Dd);
    float dot = 0.f;
#pragma unroll
    for (int j = 0; j < Dd / 4; ++j) {
      float4 a = qv4[j];
      float4 bb = kr[j];
      dot += a.x * bb.x + a.y * bb.y + a.z * bb.z + a.w * bb.w;
    }
    dot *= 0.125f;
    sc[kk] = dot;
    lmax = fmaxf(lmax, dot);
  }
  red[tid] = lmax;
  __syncthreads();
  for (int s = 128; s; s >>= 1) {
    if (tid < s) red[tid] = fmaxf(red[tid], red[tid + s]);
    __syncthreads();
  }
  float m = red[0];
  __syncthreads();
  float lsum = 0.f;
  for (int kk = tid; kk < nk; kk += 256) {
    float pp = __expf(sc[kk] - m);
    sc[kk] = pp;
    lsum += pp;
  }
  red[tid] = lsum;
  __syncthreads();
  for (int s = 128; s; s >>= 1) {
    if (tid < s) red[tid] += red[tid + s];
    __syncthreads();
  }
  float inv_denom = 1.0f / red[0];
  __syncthreads();
  int d = tid & 63, kg = tid >> 6;
  float acc = 0.f;
  for (int kk = kg; kk < nk; kk += 4)
    acc += sc[kk] * v[(((size_t)b * Ld + kk) * Hd + h) * Dd + d];
  red[tid] = acc;
  __syncthreads();
  if (kg == 0) {
    float r = red[d] + red[64 + d] + red[128 + d] + red[192 + d];
    out[(((size_t)b * Ld + t) * Hd + h) * Dd + d] = r * inv_denom;
  }
}

// ---------------------------------------------------------------------------
extern "C" void kernel_launch(void* const* d_in, const int* in_sizes, int n_in,
                              void* d_out, int out_size, void* d_ws,
                              size_t ws_size, hipStream_t stream) {
  const float* q = (const float*)d_in[0];
  const float* k = (const float*)d_in[1];
  const float* v = (const float*)d_in[2];
  const int* ridx = (const int*)d_in[4];
  float* out = (float*)d_out;

  char* ws = (char*)d_ws;
  float* M = (float*)(ws + 0);              // 262144
  int* topIdx = (int*)(ws + 262144);        //   5120
  float* csum = (float*)(ws + 272384);      // 2048*64*4 = 524288
  float* Opart = (float*)(ws + 3942400);    // 32*16*40*64*4 = 5242880
  float* mS = (float*)(ws + 9185280);       //   81920
  float* sS = (float*)(ws + 9267200);       //   81920
  const size_t need_new = 9349120;

  phase1_kernel<<<4096, 256, 0, stream>>>(q, k, v, ridx, M, csum);
  phase2_kernel<<<64, 64, 0, stream>>>(M, topIdx, csum);

  if (ws_size >= need_new) {
    phase3_kernel<<<1024, 256, 0, stream>>>(q, k, v, topIdx, csum, out, Opart,
                                            mS, sS);
    flash_combine_kernel<<<Bd * Hd * NTOP, 64, 0, stream>>>(Opart, mS, sS,
                                                            topIdx, out);
  } else {
    cumsum_write_kernel<<<Bd * Hd * NCHUNK, 64, 0, stream>>>(v, csum, out);
    attn_update_kernel<<<Bd * Hd * NTOP, 256, 0, stream>>>(q, k, v, topIdx,
                                                           out);
  }
}

// Round 14
// 94.520 us; speedup vs baseline: 2.4145x; 2.4145x over previous
//
#include <hip/hip_runtime.h>

#define Bd 4
#define Hd 8
#define Ld 2048
#define Dd 64
#define Ud 40
#define NTOP 40
#define NCHUNK 64
#define CSZ 32   // Ld / NCHUNK

#define NS 16     // k-splits for flash attention
#define FTILE 128 // Ld / NS keys per split
#define QSTR 68   // padded LDS stride (floats) for q rows
#define KSTR 68   // padded LDS stride (floats) for k/v rows
#define PSTR 132  // padded LDS stride for p rows

// ---------------------------------------------------------------------------
// Phase 1 (grid 4096, coarse role split — best measured config, R9):
//   role A (blocks 0..2047)   = compute_M (wave per (b,l), all 8 heads,
//       contiguous 2KB K-row gathers, 3 shfl/sample reduce, XCD swizzle).
//   role B (blocks 2048..4095) = chunk_sums of V.
// ---------------------------------------------------------------------------
__global__ __launch_bounds__(256) void phase1_kernel(
    const float* __restrict__ q, const float* __restrict__ k,
    const float* __restrict__ v, const int* __restrict__ ridx,
    float* __restrict__ M, float* __restrict__ csum) {
  __shared__ float red[256];
  int tid = threadIdx.x;
  if (blockIdx.x < 2048) {
    // ---- compute_M ----
    const int nblk = 2048;
    int orig = blockIdx.x;
    int bid = (orig & 7) * (nblk >> 3) + (orig >> 3);
    int gw = bid * 4 + (tid >> 6);
    int lane = tid & 63;
    int hg = lane >> 3;
    int s8 = lane & 7;
    int b = gw >> 11;
    int l = gw & (Ld - 1);

    const float* qrow = q + ((size_t)b * Ld + l) * (Hd * Dd) + lane * 8;
    float4 q0 = *reinterpret_cast<const float4*>(qrow);
    float4 q1 = *reinterpret_cast<const float4*>(qrow + 4);

    int rv = 0;
    if (lane < Ud) rv = ridx[l * Ud + lane];
    const float* kb = k + (size_t)b * Ld * (Hd * Dd);

    float mx = -INFINITY, sm = 0.f;
#pragma unroll 8
    for (int u = 0; u < Ud; ++u) {
      int kidx = __shfl(rv, u);
      const float* kr = kb + (size_t)kidx * (Hd * Dd) + lane * 8;
      float4 k0 = *reinterpret_cast<const float4*>(kr);
      float4 k1 = *reinterpret_cast<const float4*>(kr + 4);
      float dot = q0.x * k0.x + q0.y * k0.y + q0.z * k0.z + q0.w * k0.w +
                  q1.x * k1.x + q1.y * k1.y + q1.z * k1.z + q1.w * k1.w;
      dot += __shfl_xor(dot, 1);
      dot += __shfl_xor(dot, 2);
      dot += __shfl_xor(dot, 4);
      mx = fmaxf(mx, dot);
      sm += dot;
    }
    if (s8 == 0)
      M[((size_t)b * Hd + hg) * Ld + l] = mx - sm * (1.0f / (float)Ld);
  } else {
    // ---- chunk sums of V ----
    int n = blockIdx.x - 2048;  // 0..2047 = bh*NCHUNK + c
    int c = n & (NCHUNK - 1), bh = n >> 6;
    int b = bh >> 3, h = bh & 7;
    int d = tid & 63, jg = tid >> 6;
    int t0 = c * CSZ;
    float s = 0.f;
#pragma unroll
    for (int j = jg; j < CSZ; j += 4)
      s += v[(((size_t)b * Ld + t0 + j) * Hd + h) * Dd + d];
    red[tid] = s;
    __syncthreads();
    if (jg == 0)
      csum[(size_t)n * Dd + d] =
          red[d] + red[64 + d] + red[128 + d] + red[192 + d];
  }
}

// ---------------------------------------------------------------------------
// Phase 2: role A (blocks 0..31) = top-40 per (b,h) (per-lane top-3 cache);
//          role B (blocks 32..63) = exclusive scan of chunk sums.
// ---------------------------------------------------------------------------
__global__ __launch_bounds__(64) void phase2_kernel(const float* __restrict__ M,
                                                    int* __restrict__ topIdx,
                                                    float* __restrict__ csum) {
  int lane = threadIdx.x;
  if (blockIdx.x < 32) {
    int bh = blockIdx.x;
    const float* mrow = M + (size_t)bh * Ld;

    unsigned int key[32];
#pragma unroll
    for (int j = 0; j < 32; ++j) {
      unsigned int bits = __float_as_uint(mrow[lane + j * 64]);
      key[j] = (bits & 0x80000000u) ? ~bits : (bits | 0x80000000u);
    }

    const int ISENT = 1 << 30;
    unsigned int k0 = 0u, k1c = 0u, k2c = 0u;
    int i0 = ISENT, i1c = ISENT, i2c = ISENT;
#pragma unroll
    for (int j = 0; j < 32; ++j) {
      unsigned int kj = key[j];
      int idx = lane + j * 64;
      if (kj > k0) {
        k2c = k1c; i2c = i1c; k1c = k0; i1c = i0; k0 = kj; i0 = idx;
      } else if (kj > k1c) {
        k2c = k1c; i2c = i1c; k1c = kj; i1c = idx;
      } else if (kj > k2c) {
        k2c = kj; i2c = idx;
      }
    }

    for (int it = 0; it < NTOP; ++it) {
      unsigned int wk = k0;
      int wi = i0;
#pragma unroll
      for (int off = 1; off < 64; off <<= 1) {
        unsigned int ok = __shfl_xor(wk, off);
        int oi = __shfl_xor(wi, off);
        if (ok > wk || (ok == wk && oi < wi)) { wk = ok; wi = oi; }
      }
      if (lane == 0) topIdx[bh * NTOP + it] = wi;
      if (wi == i0) {
        k0 = k1c; i0 = i1c; k1c = k2c; i1c = i2c; k2c = 0u; i2c = ISENT;
        if (k0 == 0u) {
          i0 = ISENT; i1c = ISENT; i2c = ISENT;
#pragma unroll
          for (int j = 0; j < 32; ++j) {
            unsigned int kj = key[j];
            int idx = lane + j * 64;
            bool valid = (kj < wk) || (kj == wk && idx > wi);
            kj = valid ? kj : 0u;
            if (kj > k0) {
              k2c = k1c; i2c = i1c; k1c = k0; i1c = i0; k0 = kj; i0 = idx;
            } else if (kj > k1c) {
              k2c = k1c; i2c = i1c; k1c = kj; i1c = idx;
            } else if (kj > k2c) {
              k2c = kj; i2c = idx;
            }
          }
        }
      }
    }
  } else {
    int bh = blockIdx.x - 32;
    float acc = 0.f;
#pragma unroll 8
    for (int c = 0; c < NCHUNK; ++c) {
      size_t i = ((size_t)bh * NCHUNK + c) * Dd + lane;
      float s = csum[i];
      csum[i] = acc;
      acc += s;
    }
  }
}

// ---------------------------------------------------------------------------
// Phase 3 (grid 1024, coarse role split):
//   role A (blocks 0..511)   = fused split-K flash attention
//   role B (blocks 512..1023) = cumsum write (4 waves x one 32-row chunk).
// ---------------------------------------------------------------------------
__global__ __launch_bounds__(256) void phase3_kernel(
    const float* __restrict__ q, const float* __restrict__ k,
    const float* __restrict__ v, const int* __restrict__ topIdx,
    const float* __restrict__ csum, float* __restrict__ out,
    float* __restrict__ Opart, float* __restrict__ mS,
    float* __restrict__ sS) {
  __shared__ float qs[NTOP * QSTR];
  __shared__ float ks[FTILE * KSTR];
  __shared__ float p[NTOP * PSTR];
  __shared__ int ts[NTOP];
  int tid = threadIdx.x;

  if (blockIdx.x >= 512) {
    // ---- cumsum write: 4 waves x one 32-row chunk each ----
    int m = blockIdx.x - 512;
    int lane = tid & 63, w = tid >> 6;
    int blk = m * 4 + w;  // 0..2047 = bh*NCHUNK + c
    int c = blk & (NCHUNK - 1), bh = blk >> 6;
    int b = bh >> 3, h = bh & 7;
    float acc = csum[(size_t)blk * Dd + lane];
    int t0 = c * CSZ;
    const float* vp = v + (((size_t)b * Ld + t0) * Hd + h) * Dd + lane;
    float* op = out + (((size_t)b * Ld + t0) * Hd + h) * Dd + lane;
#pragma unroll 8
    for (int j = 0; j < CSZ; ++j) {
      acc += vp[(size_t)j * (Hd * Dd)];
      op[(size_t)j * (Hd * Dd)] = acc;
    }
    return;
  }

  // ---- flash attention split ----
  int split = blockIdx.x % NS;
  int bh = blockIdx.x / NS;
  int b = bh >> 3, h = bh & 7;
  int k0 = split * FTILE;

  if (tid < NTOP) ts[tid] = topIdx[bh * NTOP + tid];
  __syncthreads();

  for (int i = tid; i < NTOP * 16; i += 256) {
    int u = i >> 4, ps = i & 15;
    float4 qv = reinterpret_cast<const float4*>(
        q + (((size_t)b * Ld + ts[u]) * Hd + h) * Dd)[ps];
    *reinterpret_cast<float4*>(&qs[u * QSTR + ps * 4]) = qv;
  }
  for (int i = tid; i < FTILE * 16; i += 256) {
    int r = i >> 4, ps = i & 15;
    float4 kv = reinterpret_cast<const float4*>(
        k + (((size_t)b * Ld + k0 + r) * Hd + h) * Dd)[ps];
    *reinterpret_cast<float4*>(&ks[r * KSTR + ps * 4]) = kv;
  }
  __syncthreads();

  int ug = tid & 7, kg = tid >> 3;
  int ub = ug * 5, kb = kg * 4;
  {
    float acc[5][4] = {};
    for (int dd = 0; dd < Dd; dd += 4) {
      float4 kv[4], qv[5];
#pragma unroll
      for (int i = 0; i < 4; ++i)
        kv[i] = *reinterpret_cast<const float4*>(&ks[(kb + i) * KSTR + dd]);
#pragma unroll
      for (int i = 0; i < 5; ++i)
        qv[i] = *reinterpret_cast<const float4*>(&qs[(ub + i) * QSTR + dd]);
#pragma unroll
      for (int ui = 0; ui < 5; ++ui)
#pragma unroll
        for (int ki = 0; ki < 4; ++ki)
          acc[ui][ki] += qv[ui].x * kv[ki].x + qv[ui].y * kv[ki].y +
                         qv[ui].z * kv[ki].z + qv[ui].w * kv[ki].w;
    }
#pragma unroll
    for (int ui = 0; ui < 5; ++ui) {
      int u = ub + ui;
      int t = ts[u];
      float4 o;
      o.x = (k0 + kb + 0 <= t) ? acc[ui][0] * 0.125f : -INFINITY;
      o.y = (k0 + kb + 1 <= t) ? acc[ui][1] * 0.125f : -INFINITY;
      o.z = (k0 + kb + 2 <= t) ? acc[ui][2] * 0.125f : -INFINITY;
      o.w = (k0 + kb + 3 <= t) ? acc[ui][3] * 0.125f : -INFINITY;
      *reinterpret_cast<float4*>(&p[u * PSTR + kb]) = o;
    }
  }
  __syncthreads();

  // V tile load (into ks) overlapped with per-row softmax stats
  for (int i = tid; i < FTILE * 16; i += 256) {
    int r = i >> 4, ps = i & 15;
    float4 vv = reinterpret_cast<const float4*>(
        v + (((size_t)b * Ld + k0 + r) * Hd + h) * Dd)[ps];
    *reinterpret_cast<float4*>(&ks[r * KSTR + ps * 4]) = vv;
  }
  if (tid < NTOP * 4) {
    int u = tid >> 2, l4 = tid & 3;
    float* pr = p + u * PSTR;
    float mx = -1e30f;
#pragma unroll 8
    for (int j = l4; j < FTILE; j += 4) mx = fmaxf(mx, pr[j]);
    mx = fmaxf(mx, __shfl_xor(mx, 1));
    mx = fmaxf(mx, __shfl_xor(mx, 2));
    float sum = 0.f;
#pragma unroll 8
    for (int j = l4; j < FTILE; j += 4) {
      float pe = __expf(pr[j] - mx);
      pr[j] = pe;
      sum += pe;
    }
    sum += __shfl_xor(sum, 1);
    sum += __shfl_xor(sum, 2);
    if (l4 == 0) {
      mS[((size_t)bh * NS + split) * NTOP + u] = mx;
      sS[((size_t)bh * NS + split) * NTOP + u] = sum;
    }
  }
  __syncthreads();

  int ug2 = tid >> 5, dg = tid & 31;
  int ub2 = ug2 * 5, d2 = dg * 2;
  float acc[5][2] = {};
#pragma unroll 4
  for (int kk = 0; kk < FTILE; ++kk) {
    float2 vv = *reinterpret_cast<const float2*>(&ks[kk * KSTR + d2]);
#pragma unroll
    for (int i = 0; i < 5; ++i) {
      float pe = p[(ub2 + i) * PSTR + kk];
      acc[i][0] += pe * vv.x;
      acc[i][1] += pe * vv.y;
    }
  }
  float* ob = Opart + ((size_t)bh * NS + split) * (NTOP * Dd);
#pragma unroll
  for (int i = 0; i < 5; ++i)
    *reinterpret_cast<float2*>(&ob[(ub2 + i) * Dd + d2]) =
        make_float2(acc[i][0], acc[i][1]);
}

// ---------------------------------------------------------------------------
// Phase 4: LSE combine across NS splits + scatter-overwrite output rows.
// ---------------------------------------------------------------------------
__global__ __launch_bounds__(64) void flash_combine_kernel(
    const float* __restrict__ Opart, const float* __restrict__ mS,
    const float* __restrict__ sS, const int* __restrict__ topIdx,
    float* __restrict__ out) {
  int row = blockIdx.x;
  int u = row % NTOP, bh = row / NTOP;
  int b = bh >> 3, h = bh & 7;
  int d = threadIdx.x;
  int t = topIdx[row];

  float mg = -1e30f;
#pragma unroll
  for (int s = 0; s < NS; ++s)
    mg = fmaxf(mg, mS[((size_t)bh * NS + s) * NTOP + u]);
  float den = 0.f, o = 0.f;
#pragma unroll
  for (int s = 0; s < NS; ++s) {
    float w = __expf(mS[((size_t)bh * NS + s) * NTOP + u] - mg);
    den += w * sS[((size_t)bh * NS + s) * NTOP + u];
    o += w * Opart[(((size_t)bh * NS + s) * NTOP + u) * Dd + d];
  }
  out[(((size_t)b * Ld + t) * Hd + h) * Dd + d] = o / den;
}

// ---------------------------------------------------------------------------
// Fallback pieces (ws too small): standalone cumsum write + simple attention.
// ---------------------------------------------------------------------------
__global__ void cumsum_write_kernel(const float* __restrict__ v,
                                    const float* __restrict__ csum,
                                    float* __restrict__ out) {
  int blk = blockIdx.x;
  int c = blk & (NCHUNK - 1), bh = blk >> 6;
  int b = bh >> 3, h = bh & 7;
  int d = threadIdx.x;
  float acc = csum[(size_t)blk * Dd + d];
  int t0 = c * CSZ;
#pragma unroll 8
  for (int j = 0; j < CSZ; ++j) {
    size_t idx = (((size_t)b * Ld + t0 + j) * Hd + h) * Dd + d;
    acc += v[idx];
    out[idx] = acc;
  }
}

__global__ void attn_update_kernel(const float* __restrict__ q,
                                   const float* __restrict__ k,
                                   const float* __restrict__ v,
                                   const int* __restrict__ topIdx,
                                   float* __restrict__ out) {
  __shared__ float sc[Ld];
  __shared__ float qs[Dd];
  __shared__ float red[256];
  int tid = threadIdx.x;
  int bh = blockIdx.x / NTOP;
  int b = bh >> 3, h = bh & 7;
  int t = topIdx[blockIdx.x];

  if (tid < Dd) qs[tid] = q[(((size_t)b * Ld + t) * Hd + h) * Dd + tid];
  __syncthreads();

  int nk = t + 1;
  const float4* qv4 = reinterpret_cast<const float4*>(qs);
  float lmax = -INFINITY;
  for (int kk = tid; kk < nk; kk += 256) {
    const float4* kr = reinterpret_cast<const float4*>(
        k + (((size_t)b * Ld + kk) * Hd + h) * Dd);
    float dot = 0.f;
#pragma unroll
    for (int j = 0; j < Dd / 4; ++j) {
      float4 a = qv4[j];
      float4 bb = kr[j];
      dot += a.x * bb.x + a.y * bb.y + a.z * bb.z + a.w * bb.w;
    }
    dot *= 0.125f;
    sc[kk] = dot;
    lmax = fmaxf(lmax, dot);
  }
  red[tid] = lmax;
  __syncthreads();
  for (int s = 128; s; s >>= 1) {
    if (tid < s) red[tid] = fmaxf(red[tid], red[tid + s]);
    __syncthreads();
  }
  float m = red[0];
  __syncthreads();
  float lsum = 0.f;
  for (int kk = tid; kk < nk; kk += 256) {
    float pp = __expf(sc[kk] - m);
    sc[kk] = pp;
    lsum += pp;
  }
  red[tid] = lsum;
  __syncthreads();
  for (int s = 128; s; s >>= 1) {
    if (tid < s) red[tid] += red[tid + s];
    __syncthreads();
  }
  float inv_denom = 1.0f / red[0];
  __syncthreads();
  int d = tid & 63, kg = tid >> 6;
  float acc = 0.f;
  for (int kk = kg; kk < nk; kk += 4)
    acc += sc[kk] * v[(((size_t)b * Ld + kk) * Hd + h) * Dd + d];
  red[tid] = acc;
  __syncthreads();
  if (kg == 0) {
    float r = red[d] + red[64 + d] + red[128 + d] + red[192 + d];
    out[(((size_t)b * Ld + t) * Hd + h) * Dd + d] = r * inv_denom;
  }
}

// ---------------------------------------------------------------------------
extern "C" void kernel_launch(void* const* d_in, const int* in_sizes, int n_in,
                              void* d_out, int out_size, void* d_ws,
                              size_t ws_size, hipStream_t stream) {
  const float* q = (const float*)d_in[0];
  const float* k = (const float*)d_in[1];
  const float* v = (const float*)d_in[2];
  const int* ridx = (const int*)d_in[4];
  float* out = (float*)d_out;

  char* ws = (char*)d_ws;
  float* M = (float*)(ws + 0);              // 262144
  int* topIdx = (int*)(ws + 262144);        //   5120
  float* csum = (float*)(ws + 272384);      // 2048*64*4 = 524288
  float* Opart = (float*)(ws + 3942400);    // 32*16*40*64*4 = 5242880
  float* mS = (float*)(ws + 9185280);       //   81920
  float* sS = (float*)(ws + 9267200);       //   81920
  const size_t need_new = 9349120;

  phase1_kernel<<<4096, 256, 0, stream>>>(q, k, v, ridx, M, csum);
  phase2_kernel<<<64, 64, 0, stream>>>(M, topIdx, csum);

  if (ws_size >= need_new) {
    phase3_kernel<<<1024, 256, 0, stream>>>(q, k, v, topIdx, csum, out, Opart,
                                            mS, sS);
    flash_combine_kernel<<<Bd * Hd * NTOP, 64, 0, stream>>>(Opart, mS, sS,
                                                            topIdx, out);
  } else {
    cumsum_write_kernel<<<Bd * Hd * NCHUNK, 64, 0, stream>>>(v, csum, out);
    attn_update_kernel<<<Bd * Hd * NTOP, 256, 0, stream>>>(q, k, v, topIdx,
                                                           out);
  }
}